// Round 1
// baseline (1165.433 us; speedup 1.0000x reference)
//
#include <hip/hip_runtime.h>
#include <hip/hip_bf16.h>

// Problem: VQ-VAE quantize. N=8192 rows (dim K=512) vs M=8192 codes, fp32.
// dist = ||f||^2 - 2 f.E + ||E||^2 ; argmin over codes; EMA stats.

constexpr int N = 8192;   // rows (8*1024)
constexpr int K = 512;    // dim
constexpr int M = 8192;   // n_embed

constexpr int RB = 128;   // rows per block (score kernel)
constexpr int CB = 128;   // cols per tile
constexpr int KB = 16;    // k-chunk
constexpr int NSPLIT = 8; // column splits across blocks
constexpr int CPS = M / NSPLIT;   // 1024 cols per split
constexpr int CT = CPS / CB;      // 8 col tiles per block

// ---------------- init: c[j] = ||E_j||^2, zero counts & diff ----------------
__global__ void k_init(const float* __restrict__ E, float* __restrict__ c,
                       float* __restrict__ counts, float* __restrict__ o_diff) {
    int j = blockIdx.x * 256 + threadIdx.x;   // 8192 threads
    float s = 0.f;
    for (int d = 0; d < K; ++d) {
        float e = E[(size_t)d * M + j];       // coalesced across j
        s = fmaf(e, e, s);
    }
    c[j] = s;
    counts[j] = 0.f;
    if (j == 0) o_diff[0] = 0.f;
}

// ---------------- main argmin GEMM ----------------
__global__ __launch_bounds__(256, 2)
void k_score(const float* __restrict__ f, const float* __restrict__ E,
             const float* __restrict__ c,
             float* __restrict__ pval, int* __restrict__ pidx) {
    int bid = blockIdx.x;
    int rb = bid & 63;          // 64 row blocks
    int sp = bid >> 6;          // split id
    int rowBase = rb * RB;
    int colBase0 = sp * CPS;
    int tid = threadIdx.x;
    int tr = tid & 15, tc = tid >> 4;

    __shared__ alignas(16) float fT[KB][RB + 4];  // [kk][row], padded
    __shared__ alignas(16) float eT[KB][CB];      // [kk][col]
    __shared__ float redV[16][RB];
    __shared__ int   redI[16][RB];

    float bestV[8];
    int   bestI[8];
#pragma unroll
    for (int r = 0; r < 8; ++r) { bestV[r] = 3.4e38f; bestI[r] = 0; }

    for (int ct = 0; ct < CT; ++ct) {
        int colBase = colBase0 + ct * CB;
        float acc[2][2][4][4] = {};   // [rowgrp][colgrp][ri][ci]
        for (int k0 = 0; k0 < K; k0 += KB) {
            __syncthreads();   // LDS reuse guard
            // stage f chunk (transpose into fT[kk][row])
#pragma unroll
            for (int i = 0; i < 2; ++i) {
                int q = tid + i * 256;
                int row = q >> 2, k4 = q & 3;
                const float4 v = *(const float4*)&f[(size_t)(rowBase + row) * K + k0 + k4 * 4];
                fT[k4 * 4 + 0][row] = v.x;
                fT[k4 * 4 + 1][row] = v.y;
                fT[k4 * 4 + 2][row] = v.z;
                fT[k4 * 4 + 3][row] = v.w;
            }
            // stage e chunk (layout already [k][col])
#pragma unroll
            for (int i = 0; i < 2; ++i) {
                int q = tid + i * 256;
                int kk = q >> 5, c4 = q & 31;
                const float4 v = *(const float4*)&E[(size_t)(k0 + kk) * M + colBase + c4 * 4];
                *(float4*)&eT[kk][c4 * 4] = v;
            }
            __syncthreads();
#pragma unroll
            for (int kk = 0; kk < KB; ++kk) {
                float4 fa = *(const float4*)&fT[kk][tr * 4];
                float4 fb = *(const float4*)&fT[kk][tr * 4 + 64];
                float4 ea = *(const float4*)&eT[kk][tc * 4];
                float4 eb = *(const float4*)&eT[kk][tc * 4 + 64];
                float fr[2][4] = {{fa.x, fa.y, fa.z, fa.w}, {fb.x, fb.y, fb.z, fb.w}};
                float ec[2][4] = {{ea.x, ea.y, ea.z, ea.w}, {eb.x, eb.y, eb.z, eb.w}};
#pragma unroll
                for (int rg = 0; rg < 2; ++rg)
#pragma unroll
                    for (int ri = 0; ri < 4; ++ri)
#pragma unroll
                        for (int cg = 0; cg < 2; ++cg)
#pragma unroll
                            for (int ci = 0; ci < 4; ++ci)
                                acc[rg][cg][ri][ci] =
                                    fmaf(fr[rg][ri], ec[cg][ci], acc[rg][cg][ri][ci]);
            }
        }
        // epilogue: dist(sans ||f||^2) = c[j] - 2*acc ; running argmin
#pragma unroll
        for (int cg = 0; cg < 2; ++cg)
#pragma unroll
            for (int ci = 0; ci < 4; ++ci) {
                int j = colBase + cg * 64 + tc * 4 + ci;
                float cj = c[j];
#pragma unroll
                for (int rg = 0; rg < 2; ++rg)
#pragma unroll
                    for (int ri = 0; ri < 4; ++ri) {
                        float d = fmaf(-2.0f, acc[rg][cg][ri][ci], cj);
                        int r = rg * 4 + ri;
                        if (d < bestV[r] || (d == bestV[r] && j < bestI[r])) {
                            bestV[r] = d;
                            bestI[r] = j;
                        }
                    }
            }
    }
    // cross-thread (over tc) reduce per row
#pragma unroll
    for (int r = 0; r < 8; ++r) {
        int row = tr * 4 + (r & 3) + ((r >> 2) * 64);
        redV[tc][row] = bestV[r];
        redI[tc][row] = bestI[r];
    }
    __syncthreads();
    if (tid < RB) {
        float bv = redV[0][tid];
        int bi = redI[0][tid];
#pragma unroll
        for (int t = 1; t < 16; ++t) {
            float v = redV[t][tid];
            int i2 = redI[t][tid];
            if (v < bv || (v == bv && i2 < bi)) { bv = v; bi = i2; }
        }
        pval[(size_t)sp * N + rowBase + tid] = bv;
        pidx[(size_t)sp * N + rowBase + tid] = bi;
    }
}

// ---------------- combine splits -> final index, counts ----------------
__global__ void k_combine(const float* __restrict__ pval, const int* __restrict__ pidx,
                          int* __restrict__ indws, float* __restrict__ o_ind,
                          float* __restrict__ counts) {
    int i = blockIdx.x * 256 + threadIdx.x;   // 8192
    float bv = pval[i];
    int bi = pidx[i];
    for (int s = 1; s < NSPLIT; ++s) {
        float v = pval[(size_t)s * N + i];
        int id = pidx[(size_t)s * N + i];
        if (v < bv || (v == bv && id < bi)) { bv = v; bi = id; }
    }
    indws[i] = bi;
    o_ind[i] = (float)bi;
    atomicAdd(&counts[bi], 1.0f);
}

// ---------------- new_embed_avg init: 0.99 * embed_avg ----------------
__global__ void k_emainit(const float* __restrict__ ea, float* __restrict__ o_avg) {
    size_t i = ((size_t)blockIdx.x * 256 + threadIdx.x) * 4;
    float4 v = *(const float4*)&ea[i];
    v.x *= 0.99f; v.y *= 0.99f; v.z *= 0.99f; v.w *= 0.99f;
    *(float4*)&o_avg[i] = v;
}

// ---------------- scatter: o_avg[d][ind[i]] += 0.01*f[i][d] ----------------
__global__ void k_scatter(const float* __restrict__ f, const int* __restrict__ indws,
                          float* __restrict__ o_avg) {
    size_t el = (size_t)blockIdx.x * 256 + threadIdx.x;   // 4.19M
    int i = (int)(el >> 9);
    int d = (int)(el & 511);
    int j = indws[i];
    atomicAdd(&o_avg[(size_t)d * M + j], 0.01f * f[el]);
}

// ---------------- gather quantize + diff ----------------
__global__ __launch_bounds__(256)
void k_gather(const float* __restrict__ f, const float* __restrict__ E,
              const int* __restrict__ indws, float* __restrict__ o_q,
              float* __restrict__ o_diff) {
    int row = blockIdx.x;
    int j = indws[row];
    int tid = threadIdx.x;
    float local = 0.f;
#pragma unroll
    for (int i = 0; i < 2; ++i) {
        int d = tid + i * 256;
        float q = E[(size_t)d * M + j];
        float x = f[(size_t)row * K + d];
        o_q[(size_t)row * K + d] = x + (q - x);   // straight-through (== q numerically)
        float df = q - x;
        local = fmaf(df, df, local);
    }
#pragma unroll
    for (int off = 32; off; off >>= 1) local += __shfl_down(local, off);
    __shared__ float wsum[4];
    if ((tid & 63) == 0) wsum[tid >> 6] = local;
    __syncthreads();
    if (tid == 0) {
        float s = wsum[0] + wsum[1] + wsum[2] + wsum[3];
        atomicAdd(o_diff, s * (1.0f / 4194304.0f));
    }
}

// ---------------- new_cluster_size, n, cs (single block) ----------------
__global__ __launch_bounds__(256)
void k_cs(const float* __restrict__ cs_in, const float* __restrict__ counts,
          float* __restrict__ o_ncs, float* __restrict__ csr) {
    int tid = threadIdx.x;
    float myncs[32];
    float loc = 0.f;
#pragma unroll 32
    for (int i = 0; i < 32; ++i) {
        int j = i * 256 + tid;
        float v = 0.99f * cs_in[j] + 0.01f * counts[j];
        myncs[i] = v;
        o_ncs[j] = v;
        loc += v;
    }
#pragma unroll
    for (int off = 32; off; off >>= 1) loc += __shfl_down(loc, off);
    __shared__ float wsum[4];
    __shared__ float nsh;
    if ((tid & 63) == 0) wsum[tid >> 6] = loc;
    __syncthreads();
    if (tid == 0) nsh = wsum[0] + wsum[1] + wsum[2] + wsum[3];
    __syncthreads();
    float n = nsh;
#pragma unroll 32
    for (int i = 0; i < 32; ++i) {
        int j = i * 256 + tid;
        csr[j] = (myncs[i] + 1e-5f) / (n + 8192.0f * 1e-5f) * n;
    }
}

// ---------------- new_embed = new_embed_avg / cs ----------------
__global__ void k_div(const float* __restrict__ avg, const float* __restrict__ csr,
                      float* __restrict__ o_ne) {
    size_t idx = (size_t)blockIdx.x * 256 + threadIdx.x;
    size_t el = idx * 4;
    float4 a = *(const float4*)&avg[el];
    int j = (int)(el & (size_t)(M - 1));
    float4 cc = *(const float4*)&csr[j];
    float4 r;
    r.x = a.x / cc.x; r.y = a.y / cc.y; r.z = a.z / cc.z; r.w = a.w / cc.w;
    *(float4*)&o_ne[el] = r;
}

extern "C" void kernel_launch(void* const* d_in, const int* in_sizes, int n_in,
                              void* d_out, int out_size, void* d_ws, size_t ws_size,
                              hipStream_t stream) {
    const float* f     = (const float*)d_in[0];  // input  (8,1024,512)
    const float* E     = (const float*)d_in[1];  // embed  (512,8192)
    const float* cs_in = (const float*)d_in[2];  // cluster_size (8192)
    const float* ea    = (const float*)d_in[3];  // embed_avg (512,8192)

    float* out   = (float*)d_out;
    float* o_q    = out;                       // 4194304
    float* o_diff = out + 4194304;             // 1
    float* o_ind  = out + 4194305;             // 8192
    float* o_ne   = out + 4202497;             // 4194304
    float* o_ncs  = out + 8396801;             // 8192
    float* o_avg  = out + 8404993;             // 4194304

    float* wsf    = (float*)d_ws;
    float* c      = wsf;                  // 8192
    float* counts = wsf + 8192;           // 8192
    float* csr    = wsf + 16384;          // 8192
    int*   indws  = (int*)(wsf + 24576);  // 8192
    float* pval   = wsf + 32768;          // NSPLIT*8192
    int*   pidx   = (int*)(wsf + 98304);  // NSPLIT*8192

    k_init   <<<M / 256, 256, 0, stream>>>(E, c, counts, o_diff);
    k_score  <<<64 * NSPLIT, 256, 0, stream>>>(f, E, c, pval, pidx);
    k_combine<<<N / 256, 256, 0, stream>>>(pval, pidx, indws, o_ind, counts);
    k_emainit<<<(K * M / 4) / 256, 256, 0, stream>>>(ea, o_avg);
    k_scatter<<<(N * K) / 256, 256, 0, stream>>>(f, indws, o_avg);
    k_gather <<<N, 256, 0, stream>>>(f, E, indws, o_q, o_diff);
    k_cs     <<<1, 256, 0, stream>>>(cs_in, counts, o_ncs, csr);
    k_div    <<<(K * M / 4) / 256, 256, 0, stream>>>(o_avg, csr, o_ne);
}

// Round 3
// 1138.635 us; speedup vs baseline: 1.0235x; 1.0235x over previous
//
#include <hip/hip_runtime.h>

// VQ-VAE quantize: N=8192 rows (dim 512) vs M=8192 codes, fp32 semantics.
// Distance GEMM on MFMA via bf16 hi/lo 3-pass split + exact fp32 re-rank.

constexpr int N = 8192;
constexpr int K = 512;
constexpr int M = 8192;

typedef unsigned short ushortT;
typedef __attribute__((ext_vector_type(8))) short s8v;   // 8 bf16 (4 VGPR)
typedef __attribute__((ext_vector_type(4))) float f4v;   // MFMA acc

__device__ __forceinline__ ushortT f2bf(float x) {
    unsigned u = __float_as_uint(x);
    unsigned r = (u + 0x7FFFu + ((u >> 16) & 1u)) >> 16;
    return (ushortT)r;
}
__device__ __forceinline__ float bf2f(ushortT h) {
    return __uint_as_float(((unsigned)h) << 16);
}

typedef const __attribute__((address_space(1))) unsigned gau;
typedef __attribute__((address_space(3))) unsigned lau;
__device__ __forceinline__ void gl16(const void* g, void* l) {
    __builtin_amdgcn_global_load_lds((gau*)g, (lau*)l, 16, 0, 0);
}

__device__ __forceinline__ void top2ins(float& av, int& ai, float& bv, int& bi,
                                        float cv, int ci) {
    if (cv < av || (cv == av && ci < ai)) {
        bv = av; bi = ai; av = cv; ai = ci;
    } else if (cv < bv || (cv == bv && ci < bi)) {
        bv = cv; bi = ci;
    }
}

// ---------- prep: f -> Fh,Fl bf16 [8192][512] ----------
__global__ void k_prepF(const float* __restrict__ f, ushortT* __restrict__ Fh,
                        ushortT* __restrict__ Fl) {
    size_t i8 = ((size_t)blockIdx.x * 256 + threadIdx.x) * 8;
    float4 x0 = *(const float4*)&f[i8];
    float4 x1 = *(const float4*)&f[i8 + 4];
    float xs[8] = {x0.x, x0.y, x0.z, x0.w, x1.x, x1.y, x1.z, x1.w};
    union { s8v v; ushortT u[8]; } h, lo;
#pragma unroll
    for (int j = 0; j < 8; ++j) {
        ushortT hh = f2bf(xs[j]);
        h.u[j] = hh;
        lo.u[j] = f2bf(xs[j] - bf2f(hh));
    }
    *(s8v*)&Fh[i8] = h.v;
    *(s8v*)&Fl[i8] = lo.v;
}

// ---------- prep: E [512][8192] -> EhT,ElT bf16 [8192][512] (transpose) ----------
__global__ __launch_bounds__(256) void k_prepE(const float* __restrict__ E,
                                               ushortT* __restrict__ EhT,
                                               ushortT* __restrict__ ElT) {
    __shared__ float tile[64][65];
    int jb = blockIdx.x & 127, kb = blockIdx.x >> 7;   // 128 x 8 blocks
    int t = threadIdx.x;
    int jj = t & 63, kk0 = t >> 6;
    int j0 = jb * 64, k0 = kb * 64;
#pragma unroll
    for (int it = 0; it < 16; ++it) {
        int kk = it * 4 + kk0;
        tile[kk][jj] = E[(size_t)(k0 + kk) * M + j0 + jj];
    }
    __syncthreads();
    int r = t >> 2, ks = (t & 3) * 16;
    union { s8v v[2]; ushortT u[16]; } h, lo;
#pragma unroll
    for (int i = 0; i < 16; ++i) {
        float x = tile[ks + i][r];
        ushortT hh = f2bf(x);
        h.u[i] = hh;
        lo.u[i] = f2bf(x - bf2f(hh));
    }
    size_t o = (size_t)(j0 + r) * K + k0 + ks;
    *(s8v*)&EhT[o] = h.v[0];
    *(s8v*)&EhT[o + 8] = h.v[1];
    *(s8v*)&ElT[o] = lo.v[0];
    *(s8v*)&ElT[o + 8] = lo.v[1];
}

// ---------- c[j] = ||E_j||^2, deterministic fixed-order partials ----------
__global__ void k_cnorm(const float* __restrict__ E, float* __restrict__ pc) {
    int t = threadIdx.x;
    int jb = blockIdx.x & 31, kc = blockIdx.x >> 5;   // 32 x 8 blocks
    int j = jb * 256 + t;
    float s = 0.f;
#pragma unroll 8
    for (int k2 = 0; k2 < 64; ++k2) {
        float e = E[(size_t)(kc * 64 + k2) * M + j];
        s = fmaf(e, e, s);
    }
    pc[(size_t)kc * M + j] = s;
}

__global__ void k_cfin(const float* __restrict__ pc, float* __restrict__ c,
                       float* __restrict__ counts, float* __restrict__ o_diff) {
    int j = blockIdx.x * 256 + threadIdx.x;
    float s = 0.f;
#pragma unroll
    for (int kc = 0; kc < 8; ++kc) s += pc[(size_t)kc * M + j];
    c[j] = s;
    counts[j] = 0.f;
    if (j == 0) o_diff[0] = 0.f;
}

// ---------- main: S = f.E via 3-pass bf16 MFMA, fused per-split top-2 argmin ----------
__global__ __launch_bounds__(256, 2) void k_score(
    const ushortT* __restrict__ Fh, const ushortT* __restrict__ Fl,
    const ushortT* __restrict__ Eh, const ushortT* __restrict__ El,
    const float* __restrict__ cE,
    float* __restrict__ pval, int* __restrict__ pidx) {
    __shared__ alignas(16) ushortT aH[4096], aL[4096], bH[4096], bL[4096];  // 32 KB

    int bid = blockIdx.x;                       // 4096 blocks
    int wgs = (bid & 7) * 512 + (bid >> 3);     // XCD-contiguous chunks (bijective)
    int rb = (wgs >> 9) * 8 + (wgs & 7);        // 64 row blocks
    int cb = (wgs & 511) >> 3;                  // 64 col blocks
    int rowBase = rb * 128, colBase = cb * 128;
    int tid = threadIdx.x;
    int w = tid >> 6, l = tid & 63;
    int wr = w >> 1, wc = w & 1;
    int l15 = l & 15, g4 = l >> 4;

    size_t offA0 = (size_t)(rowBase + w * 32 + (l >> 2)) * K + (l & 3) * 8;
    size_t offA1 = offA0 + 16 * K;
    size_t offB0 = (size_t)(colBase + w * 32 + (l >> 2)) * K + (l & 3) * 8;
    size_t offB1 = offB0 + 16 * K;
    int lb = w * 1024;

    f4v acc[4][4];
#pragma unroll
    for (int m = 0; m < 4; ++m)
#pragma unroll
        for (int n = 0; n < 4; ++n) acc[m][n] = (f4v){0.f, 0.f, 0.f, 0.f};

    for (int k0 = 0; k0 < K; k0 += 32) {
        __syncthreads();
        gl16(Fh + offA0 + k0, &aH[lb]);
        gl16(Fh + offA1 + k0, &aH[lb + 512]);
        gl16(Fl + offA0 + k0, &aL[lb]);
        gl16(Fl + offA1 + k0, &aL[lb + 512]);
        gl16(Eh + offB0 + k0, &bH[lb]);
        gl16(Eh + offB1 + k0, &bH[lb + 512]);
        gl16(El + offB0 + k0, &bL[lb]);
        gl16(El + offB1 + k0, &bL[lb + 512]);
        __syncthreads();
        s8v ah[4], al[4], bh[4], bl[4];
#pragma unroll
        for (int m = 0; m < 4; ++m) {
            int ra = (wr * 64 + m * 16 + l15) * 32 + g4 * 8;
            ah[m] = *(const s8v*)&aH[ra];
            al[m] = *(const s8v*)&aL[ra];
        }
#pragma unroll
        for (int n = 0; n < 4; ++n) {
            int rbx = (wc * 64 + n * 16 + l15) * 32 + g4 * 8;
            bh[n] = *(const s8v*)&bH[rbx];
            bl[n] = *(const s8v*)&bL[rbx];
        }
#pragma unroll
        for (int m = 0; m < 4; ++m)
#pragma unroll
            for (int n = 0; n < 4; ++n) {
                acc[m][n] = __builtin_amdgcn_mfma_f32_16x16x32_bf16(ah[m], bh[n], acc[m][n], 0, 0, 0);
                acc[m][n] = __builtin_amdgcn_mfma_f32_16x16x32_bf16(ah[m], bl[n], acc[m][n], 0, 0, 0);
                acc[m][n] = __builtin_amdgcn_mfma_f32_16x16x32_bf16(al[m], bh[n], acc[m][n], 0, 0, 0);
            }
    }

    // epilogue: d = c[j] - 2*acc ; per-row top-2 within this 128-col split
    float cj[4];
#pragma unroll
    for (int n = 0; n < 4; ++n) cj[n] = cE[colBase + wc * 64 + n * 16 + l15];
    __syncthreads();
    float* rv = (float*)aH;   // [128][2 wc][2 slots]
    int* ri = (int*)bH;
#pragma unroll
    for (int m = 0; m < 4; ++m)
#pragma unroll
        for (int q = 0; q < 4; ++q) {
            float av = 3.4e38f, bv2 = 3.4e38f;
            int ai = 0x7fffffff, bi2 = 0x7fffffff;
#pragma unroll
            for (int n = 0; n < 4; ++n) {
                float d = fmaf(-2.f, acc[m][n][q], cj[n]);
                top2ins(av, ai, bv2, bi2, d, colBase + wc * 64 + n * 16 + l15);
            }
            for (int mk = 1; mk < 16; mk <<= 1) {
                float oa = __shfl_xor(av, mk), ob = __shfl_xor(bv2, mk);
                int oia = __shfl_xor(ai, mk), oib = __shfl_xor(bi2, mk);
                top2ins(av, ai, bv2, bi2, oa, oia);
                top2ins(av, ai, bv2, bi2, ob, oib);
            }
            if (l15 == 0) {
                int rowW = wr * 64 + m * 16 + g4 * 4 + q;
                rv[(rowW * 2 + wc) * 2 + 0] = av;
                rv[(rowW * 2 + wc) * 2 + 1] = bv2;
                ri[(rowW * 2 + wc) * 2 + 0] = ai;
                ri[(rowW * 2 + wc) * 2 + 1] = bi2;
            }
        }
    __syncthreads();
    if (tid < 128) {
        float av = rv[(tid * 2 + 0) * 2 + 0], bv2 = rv[(tid * 2 + 0) * 2 + 1];
        int ai = ri[(tid * 2 + 0) * 2 + 0], bi2 = ri[(tid * 2 + 0) * 2 + 1];
        top2ins(av, ai, bv2, bi2, rv[(tid * 2 + 1) * 2 + 0], ri[(tid * 2 + 1) * 2 + 0]);
        top2ins(av, ai, bv2, bi2, rv[(tid * 2 + 1) * 2 + 1], ri[(tid * 2 + 1) * 2 + 1]);
        size_t o = ((size_t)(rowBase + tid) * 64 + cb) * 2;
        pval[o] = av; pval[o + 1] = bv2;
        pidx[o] = ai; pidx[o + 1] = bi2;
    }
}

// ---------- combine: exact fp32 re-rank of near-min candidates ----------
__global__ __launch_bounds__(256) void k_combine(
    const float* __restrict__ pval, const int* __restrict__ pidx,
    const float* __restrict__ f, const float* __restrict__ E,
    const float* __restrict__ cE,
    int* __restrict__ indws, float* __restrict__ o_ind, float* __restrict__ counts) {
    int w = threadIdx.x >> 6, l = threadIdx.x & 63;
    int row = blockIdx.x * 4 + w;
    size_t base = (size_t)row * 128 + l * 2;
    float v0 = pval[base], v1 = pval[base + 1];
    int i0 = pidx[base], i1 = pidx[base + 1];
    float bv = v0; int bi = i0;
    if (v1 < bv || (v1 == bv && i1 < bi)) { bv = v1; bi = i1; }
    for (int m = 1; m < 64; m <<= 1) {
        float ov = __shfl_xor(bv, m);
        int oi = __shfl_xor(bi, m);
        if (ov < bv || (ov == bv && oi < bi)) { bv = ov; bi = oi; }
    }
    float thr = bv + 0.02f;
    float bestd = 3.4e38f; int bestj = 0x7fffffff;
#pragma unroll
    for (int s = 0; s < 2; ++s) {
        float v = s ? v1 : v0;
        int ij = s ? i1 : i0;
        unsigned long long mask = __ballot(v <= thr);
        while (mask) {
            int b = __ffsll((unsigned long long)mask) - 1;
            mask &= mask - 1;
            int j = __shfl(ij, b);
            float a = 0.f;
#pragma unroll
            for (int t2 = 0; t2 < 8; ++t2)
                a = fmaf(f[(size_t)row * K + l + 64 * t2],
                         E[(size_t)(l + 64 * t2) * M + j], a);
            for (int m = 1; m < 64; m <<= 1) a += __shfl_xor(a, m);
            float d = cE[j] - 2.f * a;
            if (d < bestd || (d == bestd && j < bestj)) { bestd = d; bestj = j; }
        }
    }
    if (l == 0) {
        indws[row] = bestj;
        o_ind[row] = (float)bestj;
        atomicAdd(&counts[bestj], 1.0f);
    }
}

// ---------- new_embed_avg init: 0.99 * embed_avg ----------
__global__ void k_emainit(const float* __restrict__ ea, float* __restrict__ o_avg) {
    size_t i = ((size_t)blockIdx.x * 256 + threadIdx.x) * 4;
    float4 v = *(const float4*)&ea[i];
    v.x *= 0.99f; v.y *= 0.99f; v.z *= 0.99f; v.w *= 0.99f;
    *(float4*)&o_avg[i] = v;
}

// ---------- scatter: o_avg[d][ind[i]] += 0.01*f[i][d] ----------
__global__ void k_scatter(const float* __restrict__ f, const int* __restrict__ indws,
                          float* __restrict__ o_avg) {
    size_t el = (size_t)blockIdx.x * 256 + threadIdx.x;
    int i = (int)(el >> 9);
    int d = (int)(el & 511);
    int j = indws[i];
    atomicAdd(&o_avg[(size_t)d * M + j], 0.01f * f[el]);
}

// ---------- gather quantize + diff ----------
__global__ __launch_bounds__(256) void k_gather(
    const float* __restrict__ f, const float* __restrict__ E,
    const int* __restrict__ indws, float* __restrict__ o_q,
    float* __restrict__ o_diff) {
    int row = blockIdx.x;
    int j = indws[row];
    int tid = threadIdx.x;
    float local = 0.f;
#pragma unroll
    for (int i = 0; i < 2; ++i) {
        int d = tid + i * 256;
        float q = E[(size_t)d * M + j];
        float x = f[(size_t)row * K + d];
        o_q[(size_t)row * K + d] = x + (q - x);
        float df = q - x;
        local = fmaf(df, df, local);
    }
#pragma unroll
    for (int off = 32; off; off >>= 1) local += __shfl_down(local, off);
    __shared__ float wsum[4];
    if ((tid & 63) == 0) wsum[tid >> 6] = local;
    __syncthreads();
    if (tid == 0) {
        float s = wsum[0] + wsum[1] + wsum[2] + wsum[3];
        atomicAdd(o_diff, s * (1.0f / 4194304.0f));
    }
}

// ---------- new_cluster_size, n, cs ----------
__global__ __launch_bounds__(256) void k_cs(const float* __restrict__ cs_in,
                                            const float* __restrict__ counts,
                                            float* __restrict__ o_ncs,
                                            float* __restrict__ csr) {
    int tid = threadIdx.x;
    float myncs[32];
    float loc = 0.f;
#pragma unroll 32
    for (int i = 0; i < 32; ++i) {
        int j = i * 256 + tid;
        float v = 0.99f * cs_in[j] + 0.01f * counts[j];
        myncs[i] = v;
        o_ncs[j] = v;
        loc += v;
    }
#pragma unroll
    for (int off = 32; off; off >>= 1) loc += __shfl_down(loc, off);
    __shared__ float wsum[4];
    __shared__ float nsh;
    if ((tid & 63) == 0) wsum[tid >> 6] = loc;
    __syncthreads();
    if (tid == 0) nsh = wsum[0] + wsum[1] + wsum[2] + wsum[3];
    __syncthreads();
    float n = nsh;
#pragma unroll 32
    for (int i = 0; i < 32; ++i) {
        int j = i * 256 + tid;
        csr[j] = (myncs[i] + 1e-5f) / (n + 8192.0f * 1e-5f) * n;
    }
}

// ---------- new_embed = new_embed_avg / cs ----------
__global__ void k_div(const float* __restrict__ avg, const float* __restrict__ csr,
                      float* __restrict__ o_ne) {
    size_t idx = (size_t)blockIdx.x * 256 + threadIdx.x;
    size_t el = idx * 4;
    float4 a = *(const float4*)&avg[el];
    int j = (int)(el & (size_t)(M - 1));
    float4 cc = *(const float4*)&csr[j];
    float4 r;
    r.x = a.x / cc.x; r.y = a.y / cc.y; r.z = a.z / cc.z; r.w = a.w / cc.w;
    *(float4*)&o_ne[el] = r;
}

extern "C" void kernel_launch(void* const* d_in, const int* in_sizes, int n_in,
                              void* d_out, int out_size, void* d_ws, size_t ws_size,
                              hipStream_t stream) {
    const float* f     = (const float*)d_in[0];
    const float* E     = (const float*)d_in[1];
    const float* cs_in = (const float*)d_in[2];
    const float* ea    = (const float*)d_in[3];

    float* out = (float*)d_out;
    float* o_q    = out;                   // 4194304
    float* o_diff = out + 4194304;         // 1
    float* o_ind  = out + 4194305;         // 8192
    float* o_ne   = out + 4202497;         // 4194304
    float* o_ncs  = out + 8396801;         // 8192
    float* o_avg  = out + 8404993;         // 4194304

    // overlays into not-yet-final output regions (freed before their writers run)
    ushortT* EhT = (ushortT*)o_q;                       // 8 MB
    ushortT* ElT = EhT + (size_t)N * K;                 // 8 MB   (o_q region: 16.78 MB)
    ushortT* Fh  = (ushortT*)(out + 4202500);           // 16B-aligned, in o_ne region
    ushortT* Fl  = Fh + (size_t)N * K;
    float*   pval = o_avg;                              // 4 MB
    int*     pidx = (int*)(o_avg + 1048576);            // 4 MB   (o_avg region: 16.78 MB)

    float* wsf    = (float*)d_ws;
    float* c      = wsf;                   // 8192
    float* counts = wsf + 8192;            // 8192
    float* csr    = wsf + 16384;           // 8192
    int*   indws  = (int*)(wsf + 24576);   // 8192
    float* pc     = wsf + 32768;           // 8*8192

    k_prepF  <<<2048, 256, 0, stream>>>(f, Fh, Fl);
    k_prepE  <<<1024, 256, 0, stream>>>(E, EhT, ElT);
    k_cnorm  <<<256, 256, 0, stream>>>(E, pc);
    k_cfin   <<<32, 256, 0, stream>>>(pc, c, counts, o_diff);
    k_score  <<<4096, 256, 0, stream>>>(Fh, Fl, EhT, ElT, c, pval, pidx);
    k_combine<<<2048, 256, 0, stream>>>(pval, pidx, f, E, c, indws, o_ind, counts);
    k_gather <<<N, 256, 0, stream>>>(f, E, indws, o_q, o_diff);      // frees EhT region
    k_emainit<<<4096, 256, 0, stream>>>(ea, o_avg);                  // frees pval region
    k_scatter<<<16384, 256, 0, stream>>>(f, indws, o_avg);
    k_cs     <<<1, 256, 0, stream>>>(cs_in, counts, o_ncs, csr);
    k_div    <<<4096, 256, 0, stream>>>(o_avg, csr, o_ne);           // frees Fh region
}